// Round 10
// baseline (1221.294 us; speedup 1.0000x reference)
//
#include <hip/hip_runtime.h>

#define DIM 512
#define NROWS 131072

typedef __attribute__((ext_vector_type(8))) __bf16 bf16x8;
typedef __attribute__((ext_vector_type(4))) float f32x4;

__device__ __forceinline__ unsigned short f2bf(float f) {
  unsigned u = __builtin_bit_cast(unsigned, f);
  return (unsigned short)((u + 0x7FFFu + ((u >> 16) & 1u)) >> 16);
}
__device__ __forceinline__ f32x4 mfma16(bf16x8 a, bf16x8 b, f32x4 c) {
  return __builtin_amdgcn_mfma_f32_16x16x32_bf16(a, b, c, 0, 0, 0);
}
__device__ __forceinline__ float sigmoid_fast(float v) {
  return 1.0f / (1.0f + __expf(-v));
}
__device__ __forceinline__ float tanh_fast(float v) {
  float e = __expf(2.0f * v);
  return 1.0f - 2.0f / (e + 1.0f);
}
__device__ __forceinline__ void gl2lds(const void* g, void* l) {
  __builtin_amdgcn_global_load_lds(
      (const __attribute__((address_space(1))) unsigned int*)g,
      (__attribute__((address_space(3))) unsigned int*)l, 16, 0, 0);
}

// ---------------------------------------------------------------------------
// Weight pre-pack: fp32 W[out=512][in=512] -> bf16 B-fragments.
// Frag (gate g, kstep f, colfrag c): lane l holds 8 bf16 =
//   W[c*16 + (l&15)][f*32 + (l>>4)*8 + 0..7]
// elem index = ((g*16+f)*32 + c)*512 + l*8 + e.  Gates: rx,zx,rh,zh,nx,nh.
// ---------------------------------------------------------------------------
__global__ void prepack_weights(const float* __restrict__ W0, const float* __restrict__ W1,
                                const float* __restrict__ W2, const float* __restrict__ W3,
                                const float* __restrict__ W4, const float* __restrict__ W5,
                                unsigned short* __restrict__ out) {
  int idx = blockIdx.x * 256 + threadIdx.x;
  int e = idx & 7;
  int l = (idx >> 3) & 63;
  int c = (idx >> 9) & 31;
  int f = (idx >> 14) & 15;
  int g = idx >> 18;
  const float* W = (g == 0) ? W0 : (g == 1) ? W1 : (g == 2) ? W2
                 : (g == 3) ? W3 : (g == 4) ? W4 : W5;
  int row = c * 16 + (l & 15);
  int kk  = f * 32 + ((l >> 4) << 3) + e;
  out[idx] = f2bf(W[row * DIM + kk]);
}

// ===========================================================================
// m97-template GEMMs: 128x128 tile, 256 thr / 4 waves (wave = 64r x 64c),
// 32 KB LDS (A dbuf 2x8K frag-layout bf16 + B dbuf 2x8K), 3 blocks/CU,
// plain 2-phase loop: {stage f+1 (issue-early); compute f; write-late;
// __syncthreads}.  B via linear gl2lds from packed weights (L2-resident).
// A reg-staged from fp32 with frag-layout ds_write (<=4-way write conflict).
// ===========================================================================

// ---- GEMM1: C[N x 1024] = [x|h] @ [Wrx|Wrh ; Wzx|Wzh]^T ----
//   n<4: r-tiles -> rh = sigmoid(.)*h -> rhws bf16.  n>=4: z -> sigmoid -> zout.
__global__ __launch_bounds__(256, 3)
void gemm_rz(const float* __restrict__ x, const float* __restrict__ h,
             const unsigned char* __restrict__ WB,
             const float* __restrict__ b_rx, const float* __restrict__ b_rh,
             const float* __restrict__ b_zx, const float* __restrict__ b_zh,
             unsigned short* __restrict__ rhws, float* __restrict__ zout) {
  __shared__ __align__(1024) unsigned char ldsA[2][8192];
  __shared__ __align__(1024) unsigned char ldsB[2][8192];

  const int tid = threadIdx.x, lane = tid & 63, w = tid >> 6;
  const int wr = w & 1, wc = w >> 1, lr = lane & 15, lk = lane >> 4;

  const int bid = blockIdx.x;                 // 8192 = 1024 panels x 8 ntiles
  const int t = (bid & 7) * 1024 + (bid >> 3);
  const int panel = t >> 3, n = t & 7;
  const int row0 = panel * 128;
  const bool isR = (n < 4);
  const int gx = isR ? 0 : 1, gh = isR ? 2 : 3, c0 = (n & 3) * 8;

  const int srow = tid >> 1, skh = tid & 1;   // staging: row 0..127, k-half

  float4 ar0, ar1, ar2, ar3;
  auto issueA = [&](int f) {
    const float* src = (f < 16) ? x : h;
    const float* p = src + (size_t)(row0 + srow) * DIM + (f & 15) * 32 + skh * 16;
    ar0 = ((const float4*)p)[0]; ar1 = ((const float4*)p)[1];
    ar2 = ((const float4*)p)[2]; ar3 = ((const float4*)p)[3];
  };
  auto writeA = [&](int buf) {
    union { unsigned short us[8]; uint4 v; } p0, p1;
    p0.us[0]=f2bf(ar0.x); p0.us[1]=f2bf(ar0.y); p0.us[2]=f2bf(ar0.z); p0.us[3]=f2bf(ar0.w);
    p0.us[4]=f2bf(ar1.x); p0.us[5]=f2bf(ar1.y); p0.us[6]=f2bf(ar1.z); p0.us[7]=f2bf(ar1.w);
    p1.us[0]=f2bf(ar2.x); p1.us[1]=f2bf(ar2.y); p1.us[2]=f2bf(ar2.z); p1.us[3]=f2bf(ar2.w);
    p1.us[4]=f2bf(ar3.x); p1.us[5]=f2bf(ar3.y); p1.us[6]=f2bf(ar3.z); p1.us[7]=f2bf(ar3.w);
    const int rf = srow >> 4, r15 = srow & 15;
    *(uint4*)&ldsA[buf][rf * 1024 + ((skh * 2 + 0) * 16 + r15) * 16] = p0.v;
    *(uint4*)&ldsA[buf][rf * 1024 + ((skh * 2 + 1) * 16 + r15) * 16] = p1.v;
  };
  auto stageB = [&](int g, int fk, int buf) {
    const unsigned char* s = WB + ((size_t)((g * 16 + fk) * 32 + c0) << 10);
    gl2lds(s + tid * 16, &ldsB[buf][tid * 16]);
    gl2lds(s + 4096 + tid * 16, &ldsB[buf][4096 + tid * 16]);
  };

  f32x4 acc[4][4] = {};
  auto compute = [&](int buf) {
    bf16x8 af[4], bfr[4];
#pragma unroll
    for (int rf = 0; rf < 4; ++rf)
      af[rf] = *(const bf16x8*)&ldsA[buf][(wr * 4 + rf) * 1024 + lane * 16];
#pragma unroll
    for (int cf = 0; cf < 4; ++cf)
      bfr[cf] = *(const bf16x8*)&ldsB[buf][(wc * 4 + cf) * 1024 + lane * 16];
    __builtin_amdgcn_s_setprio(1);
#pragma unroll
    for (int rf = 0; rf < 4; ++rf)
#pragma unroll
      for (int cf = 0; cf < 4; ++cf)
        acc[rf][cf] = mfma16(af[rf], bfr[cf], acc[rf][cf]);
    __builtin_amdgcn_s_setprio(0);
  };

  issueA(0); stageB(gx, 0, 0); writeA(0);
  __syncthreads();
#pragma unroll 1
  for (int f = 0; f < 32; ++f) {
    const int buf = f & 1;
    if (f < 31) {
      const int fn = f + 1;
      issueA(fn);                                   // global loads in flight
      stageB((fn < 16) ? gx : gh, fn & 15, buf ^ 1);
    }
    compute(buf);
    if (f < 31) writeA(buf ^ 1);                    // write-late (T14)
    __syncthreads();
  }

  // epilogue
  const float* bx = isR ? b_rx : b_zx;
  const float* bh = isR ? b_rh : b_zh;
#pragma unroll
  for (int cf = 0; cf < 4; ++cf) {
    const int col = ((n & 3) * 8 + wc * 4 + cf) * 16 + lr;
    const float bsum = bx[col] + bh[col];
#pragma unroll
    for (int rf = 0; rf < 4; ++rf) {
#pragma unroll
      for (int j = 0; j < 4; ++j) {
        const int row = row0 + wr * 64 + rf * 16 + lk * 4 + j;
        const size_t off = (size_t)row * DIM + col;
        const float v = acc[rf][cf][j] + bsum;
        if (isR) rhws[off] = f2bf(sigmoid_fast(v) * h[off]);  // h L2-hot
        else     zout[off] = sigmoid_fast(v);
      }
    }
  }
}

// ---- GEMM2: C[N x 512] = [x|rh] @ [Wnx|Wnh]^T; combine epilogue ----
__global__ __launch_bounds__(256, 3)
void gemm_n(const float* __restrict__ x, const float* __restrict__ h,
            const unsigned char* __restrict__ WB,
            const unsigned short* __restrict__ rhws,
            const float* __restrict__ b_nx, const float* __restrict__ b_nh,
            float* __restrict__ out) {
  __shared__ __align__(1024) unsigned char ldsA[2][8192];
  __shared__ __align__(1024) unsigned char ldsB[2][8192];

  const int tid = threadIdx.x, lane = tid & 63, w = tid >> 6;
  const int wr = w & 1, wc = w >> 1, lr = lane & 15, lk = lane >> 4;

  const int bid = blockIdx.x;                 // 4096 = 1024 panels x 4 ntiles
  const int t = (bid & 7) * 512 + (bid >> 3);
  const int panel = t >> 2, n = t & 3;
  const int row0 = panel * 128;
  const int c0 = n * 8;

  const int srow = tid >> 1, skh = tid & 1;

  float4 ar0, ar1, ar2, ar3;
  auto issueA = [&](int fk) {
    const float* p = x + (size_t)(row0 + srow) * DIM + fk * 32 + skh * 16;
    ar0 = ((const float4*)p)[0]; ar1 = ((const float4*)p)[1];
    ar2 = ((const float4*)p)[2]; ar3 = ((const float4*)p)[3];
  };
  auto writeA = [&](int buf) {
    union { unsigned short us[8]; uint4 v; } p0, p1;
    p0.us[0]=f2bf(ar0.x); p0.us[1]=f2bf(ar0.y); p0.us[2]=f2bf(ar0.z); p0.us[3]=f2bf(ar0.w);
    p0.us[4]=f2bf(ar1.x); p0.us[5]=f2bf(ar1.y); p0.us[6]=f2bf(ar1.z); p0.us[7]=f2bf(ar1.w);
    p1.us[0]=f2bf(ar2.x); p1.us[1]=f2bf(ar2.y); p1.us[2]=f2bf(ar2.z); p1.us[3]=f2bf(ar2.w);
    p1.us[4]=f2bf(ar3.x); p1.us[5]=f2bf(ar3.y); p1.us[6]=f2bf(ar3.z); p1.us[7]=f2bf(ar3.w);
    const int rf = srow >> 4, r15 = srow & 15;
    *(uint4*)&ldsA[buf][rf * 1024 + ((skh * 2 + 0) * 16 + r15) * 16] = p0.v;
    *(uint4*)&ldsA[buf][rf * 1024 + ((skh * 2 + 1) * 16 + r15) * 16] = p1.v;
  };
  auto stageRH = [&](int fk, int buf) {        // bf16 rh -> frag LDS, gl2lds
#pragma unroll
    for (int it = 0; it < 2; ++it) {
      const int cell = it * 256 + tid;         // 0..511
      const int rf = cell >> 6, l = cell & 63;
      const int row = rf * 16 + (l & 15);
      const unsigned short* s = rhws + (size_t)(row0 + row) * DIM
                                + fk * 32 + ((l >> 4) & 3) * 8;
      gl2lds(s, &ldsA[buf][cell * 16]);
    }
  };
  auto stageB = [&](int g, int fk, int buf) {
    const unsigned char* s = WB + ((size_t)((g * 16 + fk) * 32 + c0) << 10);
    gl2lds(s + tid * 16, &ldsB[buf][tid * 16]);
    gl2lds(s + 4096 + tid * 16, &ldsB[buf][4096 + tid * 16]);
  };

  f32x4 acc[4][4] = {};
  auto compute = [&](int buf) {
    bf16x8 af[4], bfr[4];
#pragma unroll
    for (int rf = 0; rf < 4; ++rf)
      af[rf] = *(const bf16x8*)&ldsA[buf][(wr * 4 + rf) * 1024 + lane * 16];
#pragma unroll
    for (int cf = 0; cf < 4; ++cf)
      bfr[cf] = *(const bf16x8*)&ldsB[buf][(wc * 4 + cf) * 1024 + lane * 16];
    __builtin_amdgcn_s_setprio(1);
#pragma unroll
    for (int rf = 0; rf < 4; ++rf)
#pragma unroll
      for (int cf = 0; cf < 4; ++cf)
        acc[rf][cf] = mfma16(af[rf], bfr[cf], acc[rf][cf]);
    __builtin_amdgcn_s_setprio(0);
  };

  issueA(0); stageB(4, 0, 0); writeA(0);
  __syncthreads();
#pragma unroll 1
  for (int f = 0; f < 32; ++f) {
    const int buf = f & 1;
    const int fn = f + 1;
    if (f < 31) {
      if (fn < 16) issueA(fn);
      stageB((fn < 16) ? 4 : 5, fn & 15, buf ^ 1);
      if (fn >= 16) stageRH(fn & 15, buf ^ 1);
    }
    compute(buf);
    if (f < 31 && fn < 16) writeA(buf ^ 1);
    __syncthreads();
  }

  // epilogue: n = tanh(acc+b); out = (1-z)*n + z*h  (z staged in out by GEMM1)
#pragma unroll
  for (int cf = 0; cf < 4; ++cf) {
    const int col = (n * 8 + wc * 4 + cf) * 16 + lr;
    const float bn = b_nx[col] + b_nh[col];
#pragma unroll
    for (int rf = 0; rf < 4; ++rf) {
#pragma unroll
      for (int j = 0; j < 4; ++j) {
        const int row = row0 + wr * 64 + rf * 16 + lk * 4 + j;
        const size_t off = (size_t)row * DIM + col;
        const float nv = tanh_fast(acc[rf][cf][j] + bn);
        const float zv = out[off];
        out[off] = (1.0f - zv) * nv + zv * h[off];
      }
    }
  }
}

extern "C" void kernel_launch(void* const* d_in, const int* in_sizes, int n_in,
                              void* d_out, int out_size, void* d_ws, size_t ws_size,
                              hipStream_t stream) {
  const float* x    = (const float*)d_in[0];
  const float* h    = (const float*)d_in[1];
  const float* W_rx = (const float*)d_in[2];
  const float* b_rx = (const float*)d_in[3];
  const float* W_rh = (const float*)d_in[4];
  const float* b_rh = (const float*)d_in[5];
  const float* W_zx = (const float*)d_in[6];
  const float* b_zx = (const float*)d_in[7];
  const float* W_zh = (const float*)d_in[8];
  const float* b_zh = (const float*)d_in[9];
  const float* W_nx = (const float*)d_in[10];
  const float* b_nx = (const float*)d_in[11];
  const float* W_nh = (const float*)d_in[12];
  const float* b_nh = (const float*)d_in[13];

  unsigned char* ws = (unsigned char*)d_ws;
  unsigned short* wpack = (unsigned short*)ws;                  // 3 MiB
  unsigned short* rhws  = (unsigned short*)(ws + (4ull << 20)); // 128 MiB (proven)

  // gate order: rx, zx, rh, zh, nx, nh
  prepack_weights<<<6144, 256, 0, stream>>>(W_rx, W_zx, W_rh, W_zh, W_nx, W_nh, wpack);
  gemm_rz<<<8192, 256, 0, stream>>>(x, h, (const unsigned char*)wpack,
                                    b_rx, b_rh, b_zx, b_zh, rhws, (float*)d_out);
  gemm_n<<<4096, 256, 0, stream>>>(x, h, (const unsigned char*)wpack,
                                   rhws, b_nx, b_nh, (float*)d_out);
}